// Round 5
// baseline (298.044 us; speedup 1.0000x reference)
//
#include <hip/hip_runtime.h>
#include <hip/hip_bf16.h>

// Problem constants
#define CIN   128
#define COUT  64
#define HW    16384   // 128*128

typedef __hip_bfloat16 bf16;

// Workspace layout (float offsets) — total 2,152,576 floats = 8.6 MB
#define OFF_XT    0u          // bf16[2][64][16384]  xt            (1048576 f-equiv)
#define OFF_PS    1048576u    // bf16[512 blk][64 k][64 o] partial bin sums (1048576 f-equiv)
#define OFF_PC    2097152u    // f32 [2][64][256]    partial bin counts
#define OFF_MEANS 2129920u    // f32 [2][64][64]
#define OFF_DIAG  2138112u    // f32 [2][64]         m^T C^-1 m
#define OFF_INV   2138240u    // f32 [64][64]        inv(cov) (symmetric)
#define OFF_ADJM  2142336u    // f32 [2][64][64]     adj @ means
#define OFF_BNP   2150528u    // f32 [32 oc][16 b*tile] float4 {s0,s1,ss0,ss1}

__device__ __forceinline__ float rdlane(float v, int lane) {
  return __int_as_float(__builtin_amdgcn_readlane(__float_as_int(v), lane));
}
__device__ __forceinline__ unsigned short f2bfu(float f) {
  union { bf16 h; unsigned short u; } cv; cv.h = __float2bfloat16(f); return cv.u;
}
__device__ __forceinline__ float bf2f(unsigned short u) {
  union { unsigned int i; float f; } cv; cv.i = ((unsigned int)u) << 16; return cv.f;
}

// K1: xt = einsum('bchw,co->bohw') (bf16 out) + per-block bin partials; block 512 = inv(Wm Wm^T).
// LDS-staged GEMM: block = 64 px x 64 o x 128 c. x tile 32KB + Wft 32KB = 64KB -> 2 blocks/CU
// (8 waves/CU). Compute from LDS: thread = 4px x 4o; per c: 2 ds_read_b128 + 16 FMA.
// x read: 256B unique/wave (2-way bank alias = free); Wft read: 64B, 16-way broadcast = free.
__global__ __launch_bounds__(256, 2) void k1_xt_bins_inv(
    const float* __restrict__ x, const int* __restrict__ index,
    const float* __restrict__ Wft, const float* __restrict__ Wm,
    float* __restrict__ ws)
{
  __shared__ __align__(16) float smem[16384];   // 64 KB
  const int blk = blockIdx.x, tid = threadIdx.x;
  if (blk < 512) {
    float* xl = smem;          // [128 c][64 px]
    float* wl = smem + 8192;   // [128 c][64 o]
    const int b = blk >> 8, ps = blk & 255;
    // ---- stage x slab (64 px x 128 c) and all of Wft, bulk-coalesced
    const float* xg = x + (size_t)b * CIN * HW + ps * 64;
#pragma unroll
    for (int j = 0; j < 8; ++j) {
      const int fj = j * 256 + tid;            // float4 id
      const int c = fj >> 4, q4 = (fj & 15) * 4;
      *(float4*)&xl[c * 64 + q4] = *(const float4*)(xg + (size_t)c * HW + q4);
      *(float4*)&wl[c * 64 + q4] = *(const float4*)(Wft + c * 64 + q4);
    }
    __syncthreads();
    // ---- register-tiled compute
    const int px_grp = tid & 15, o_grp = tid >> 4;
    const int px = ps * 64 + px_grp * 4, o0 = o_grp * 4;
    float acc[16];
#pragma unroll
    for (int j = 0; j < 16; ++j) acc[j] = 0.f;
#pragma unroll 8
    for (int c = 0; c < 128; ++c) {
      const float4 xv = *(const float4*)&xl[c * 64 + px_grp * 4];
      const float4 wv = *(const float4*)&wl[c * 64 + o0];
      acc[ 0]=fmaf(xv.x,wv.x,acc[ 0]); acc[ 1]=fmaf(xv.y,wv.x,acc[ 1]);
      acc[ 2]=fmaf(xv.z,wv.x,acc[ 2]); acc[ 3]=fmaf(xv.w,wv.x,acc[ 3]);
      acc[ 4]=fmaf(xv.x,wv.y,acc[ 4]); acc[ 5]=fmaf(xv.y,wv.y,acc[ 5]);
      acc[ 6]=fmaf(xv.z,wv.y,acc[ 6]); acc[ 7]=fmaf(xv.w,wv.y,acc[ 7]);
      acc[ 8]=fmaf(xv.x,wv.z,acc[ 8]); acc[ 9]=fmaf(xv.y,wv.z,acc[ 9]);
      acc[10]=fmaf(xv.z,wv.z,acc[10]); acc[11]=fmaf(xv.w,wv.z,acc[11]);
      acc[12]=fmaf(xv.x,wv.w,acc[12]); acc[13]=fmaf(xv.y,wv.w,acc[13]);
      acc[14]=fmaf(xv.z,wv.w,acc[14]); acc[15]=fmaf(xv.w,wv.w,acc[15]);
    }
    // ---- write xt (bf16)
    unsigned short* xtu = (unsigned short*)(ws + OFF_XT);
#pragma unroll
    for (int oj = 0; oj < 4; ++oj) {
      ushort4 u;
      u.x = f2bfu(acc[oj*4+0]); u.y = f2bfu(acc[oj*4+1]);
      u.z = f2bfu(acc[oj*4+2]); u.w = f2bfu(acc[oj*4+3]);
      *(ushort4*)(xtu + (size_t)(b * 64 + o0 + oj) * HW + px) = u;
    }
    // ---- bin partials (reuse LDS after compute done)
    const int4 kv = *(const int4*)(index + b * HW + px);
    const int kk[4] = {kv.x, kv.y, kv.z, kv.w};
    __syncthreads();                       // all LDS compute reads done
    float* bins = smem;                    // [64 k][68] padded
    float* cnt  = smem + 64 * 68;          // [64]
    for (int i = tid; i < 64 * 68 + 64; i += 256) smem[i] = 0.f;
    __syncthreads();
#pragma unroll
    for (int pj = 0; pj < 4; ++pj) {
      const int kb = kk[pj] * 68 + o0;
      atomicAdd(&bins[kb    ], acc[ 0 + pj]);
      atomicAdd(&bins[kb + 1], acc[ 4 + pj]);
      atomicAdd(&bins[kb + 2], acc[ 8 + pj]);
      atomicAdd(&bins[kb + 3], acc[12 + pj]);
    }
    if (o_grp == 0) {   // exactly one thread per px (R3 lesson: guard the o replication)
#pragma unroll
      for (int pj = 0; pj < 4; ++pj) atomicAdd(&cnt[kk[pj]], 1.f);
    }
    __syncthreads();
    // ---- dump partials as bf16: [64 k][64 o]
    unsigned short* pb = (unsigned short*)(ws + OFF_PS) + (size_t)blk * 4096;
    {
      const int k = tid >> 2, ob = (tid & 3) * 16;
#pragma unroll
      for (int q = 0; q < 4; ++q) {
        const float4 v = *(const float4*)&bins[k * 68 + ob + q * 4];
        ushort4 u;
        u.x = f2bfu(v.x); u.y = f2bfu(v.y); u.z = f2bfu(v.z); u.w = f2bfu(v.w);
        *(ushort4*)(pb + k * 64 + ob + q * 4) = u;
      }
    }
    if (tid < 64) ws[OFF_PC + (size_t)(b * 64 + tid) * 256 + ps] = cnt[tid];
  } else {
    // ---- inverse block: cov = Wm Wm^T (regs), Gauss-Jordan in LDS (SPD, no pivoting)
    float* wm = smem;  // [64][68]
    for (int e = tid; e < 4096; e += 256) wm[(e >> 6) * 68 + (e & 63)] = Wm[e];
    __syncthreads();
    const int i0 = (tid >> 4) << 2, j0 = (tid & 15) << 2;
    float c4[16];
#pragma unroll
    for (int q = 0; q < 16; ++q) c4[q] = 0.f;
    for (int cq = 0; cq < 64; cq += 4) {
      float4 a[4], bb[4];
#pragma unroll
      for (int ii = 0; ii < 4; ++ii) a[ii]  = *(const float4*)&wm[(i0+ii)*68 + cq];
#pragma unroll
      for (int jj = 0; jj < 4; ++jj) bb[jj] = *(const float4*)&wm[(j0+jj)*68 + cq];
#pragma unroll
      for (int ii = 0; ii < 4; ++ii)
#pragma unroll
        for (int jj = 0; jj < 4; ++jj)
          c4[ii*4+jj] = fmaf(a[ii].x, bb[jj].x, fmaf(a[ii].y, bb[jj].y,
                        fmaf(a[ii].z, bb[jj].z, fmaf(a[ii].w, bb[jj].w, c4[ii*4+jj]))));
    }
    __syncthreads();
#pragma unroll
    for (int ii = 0; ii < 4; ++ii)
#pragma unroll
      for (int jj = 0; jj < 4; ++jj)
        smem[(i0+ii)*68 + (j0+jj)] = c4[ii*4+jj];
    __syncthreads();
    if (tid < 64) {
      __builtin_amdgcn_s_setprio(3);
      float r[64];
#pragma unroll
      for (int j = 0; j < 64; ++j) r[j] = smem[tid * 68 + j];
#pragma unroll
      for (int k = 0; k < 64; ++k) {
        const float piv = rdlane(r[k], k);
        const float rp  = 1.0f / piv;
        const float a   = (tid == k) ? (rp - 1.0f) : (-r[k] * rp);
#pragma unroll
        for (int j = 0; j < 64; ++j) {
          const float s = rdlane(r[j], k);
          r[j] = fmaf(a, s, r[j]);
        }
        r[k] = (tid == k) ? rp : a;
      }
      __builtin_amdgcn_s_setprio(0);
#pragma unroll
      for (int j = 0; j < 64; ++j) ws[OFF_INV + tid * 64 + j] = r[j];
    }
  }
}

// K1.5: reduce bin partials -> means; diag[b][k] = m^T C^-1 m. 128 blocks x 1024 thr.
__global__ __launch_bounds__(1024) void k15_means_diag(float* __restrict__ ws)
{
  __shared__ float red[1024];
  __shared__ float lds_c[4];
  __shared__ float lds_m[64];
  const int blk = blockIdx.x, t = threadIdx.x;
  const int b = blk >> 6, k = blk & 63;
  const int o = t & 63, chunk = t >> 6;
  const unsigned short* psu = (const unsigned short*)(ws + OFF_PS);
  float s = 0.f;
#pragma unroll
  for (int i = 0; i < 16; ++i) {
    const int slab = chunk * 16 + i;
    s += bf2f(psu[(size_t)(b * 256 + slab) * 4096 + k * 64 + o]);
  }
  red[chunk * 64 + o] = s;
  float cv = 0.f;
  if (t < 256) cv = ws[OFF_PC + (size_t)(b * 64 + k) * 256 + t];
#pragma unroll
  for (int m = 32; m; m >>= 1) cv += __shfl_xor(cv, m, 64);
  if (t < 256 && (t & 63) == 0) lds_c[t >> 6] = cv;
  __syncthreads();
  if (t < 64) {
    float m_raw = 0.f;
#pragma unroll
    for (int ch = 0; ch < 16; ++ch) m_raw += red[ch * 64 + o];
    const float cnt = lds_c[0] + lds_c[1] + lds_c[2] + lds_c[3];
    const float denom = cnt + ((cnt == 0.f) ? 1.f : 0.f);
    const float m = m_raw / denom;
    ws[OFF_MEANS + (size_t)(b * 64 + k) * 64 + o] = m;
    lds_m[o] = m;
    float inner = 0.f;  // inv symmetric -> coalesced column reads
#pragma unroll 8
    for (int d = 0; d < 64; ++d) inner = fmaf(ws[OFF_INV + d * 64 + o], lds_m[d], inner);
    float p = m * inner;
#pragma unroll
    for (int mm = 32; mm; mm >>= 1) p += __shfl_xor(p, mm, 64);
    if (o == 0) ws[OFF_DIAG + b * 64 + k] = p;
  }
}

// K2: T = means@inv ; q = diag_i+diag_j-2*T_i.m_j ; adj = exp(-sqrt(max(q,1e-12))) ; AM = adj@means
__global__ __launch_bounds__(256) void k2_adj(float* __restrict__ ws)
{
  __shared__ __align__(16) float means_s[64 * 68];
  __shared__ __align__(16) float inv_s[64 * 68];
  __shared__ __align__(16) float T_s[8 * 68];
  __shared__ __align__(16) float adj_s[8 * 68];
  __shared__ float diag_s[64];
  const int b = blockIdx.x >> 3;
  const int i0 = (blockIdx.x & 7) << 3;
  const int t = threadIdx.x;
  const float* mg = ws + OFF_MEANS + b * 4096;
  for (int e = t; e < 4096; e += 256) means_s[(e >> 6) * 68 + (e & 63)] = mg[e];
  const float* ig = ws + OFF_INV;
  for (int e = t; e < 4096; e += 256) inv_s[(e >> 6) * 68 + (e & 63)] = ig[e];
  if (t < 64) diag_s[t] = ws[OFF_DIAG + b * 64 + t];
  __syncthreads();
  if (t < 128) {
    const int i = t >> 4, d0 = (t & 15) << 2;
    float4 acc = {0.f, 0.f, 0.f, 0.f};
    for (int c = 0; c < 64; ++c) {
      const float mv = means_s[(i0 + i) * 68 + c];
      const float4 iv = *(const float4*)&inv_s[c * 68 + d0];
      acc.x = fmaf(mv, iv.x, acc.x); acc.y = fmaf(mv, iv.y, acc.y);
      acc.z = fmaf(mv, iv.z, acc.z); acc.w = fmaf(mv, iv.w, acc.w);
    }
    *(float4*)&T_s[i * 68 + d0] = acc;
  }
  __syncthreads();
  {
    const int i = t >> 5, jb = t & 31;
#pragma unroll
    for (int jj = 0; jj < 2; ++jj) {
      const int j = jb + (jj << 5);
      float4 p4 = {0.f, 0.f, 0.f, 0.f};
      for (int dq = 0; dq < 64; dq += 4) {
        const float4 tv = *(const float4*)&T_s[i * 68 + dq];
        const float4 mv = *(const float4*)&means_s[j * 68 + dq];
        p4.x = fmaf(tv.x, mv.x, p4.x); p4.y = fmaf(tv.y, mv.y, p4.y);
        p4.z = fmaf(tv.z, mv.z, p4.z); p4.w = fmaf(tv.w, mv.w, p4.w);
      }
      const float p = (p4.x + p4.y) + (p4.z + p4.w);
      const float q = diag_s[i0 + i] + diag_s[j] - 2.f * p;
      adj_s[i * 68 + j] = __expf(-sqrtf(fmaxf(q, 1e-12f)));
    }
  }
  __syncthreads();
  if (t < 128) {
    const int i = t >> 4, oq = (t & 15) << 2;
    float4 am = {0.f, 0.f, 0.f, 0.f};
    for (int j = 0; j < 64; ++j) {
      const float av = adj_s[i * 68 + j];
      const float4 mv = *(const float4*)&means_s[j * 68 + oq];
      am.x = fmaf(av, mv.x, am.x); am.y = fmaf(av, mv.y, am.y);
      am.z = fmaf(av, mv.z, am.z); am.w = fmaf(av, mv.w, am.w);
    }
    *(float4*)(ws + OFF_ADJM + (size_t)(b * 64 + i0 + i) * 64 + oq) = am;
  }
}

// K3: BN partial stats of f = relu(xt + adj_means[idx]). 512 blocks: (b, o-pair oc, 2048-px tile).
__global__ __launch_bounds__(256) void k3_bnstats(const int* __restrict__ index,
                                                  float* __restrict__ ws)
{
  __shared__ float am_s[128];   // [64 k][2 o]
  __shared__ float red[4];
  const int blk = blockIdx.x, t = threadIdx.x;
  const int b = blk >> 8, oc = (blk >> 3) & 31, tile = blk & 7;
  const int o0 = oc * 2;
  if (t < 128) am_s[t] = ws[OFF_ADJM + (size_t)(b * 64 + (t >> 1)) * 64 + o0 + (t & 1)];
  if (t < 4) red[t] = 0.f;
  __syncthreads();
  const int lane = t & 63, w = t >> 6;
  const unsigned short* xtu = (const unsigned short*)(ws + OFF_XT);
  float s0 = 0.f, s1 = 0.f, q0 = 0.f, q1 = 0.f;
#pragma unroll
  for (int q = 0; q < 2; ++q) {
    const int px = tile * 2048 + (w * 2 + q) * 256 + lane * 4;
    const int4 kv = *(const int4*)(index + b * HW + px);
    const ushort4 u0 = *(const ushort4*)(xtu + (size_t)(b * 64 + o0    ) * HW + px);
    const ushort4 u1 = *(const ushort4*)(xtu + (size_t)(b * 64 + o0 + 1) * HW + px);
    const int kk[4] = {kv.x, kv.y, kv.z, kv.w};
    const float x0[4] = {bf2f(u0.x), bf2f(u0.y), bf2f(u0.z), bf2f(u0.w)};
    const float x1[4] = {bf2f(u1.x), bf2f(u1.y), bf2f(u1.z), bf2f(u1.w)};
#pragma unroll
    for (int j = 0; j < 4; ++j) {
      const float2 am = *(const float2*)&am_s[kk[j] * 2];
      const float f0 = fmaxf(x0[j] + am.x, 0.f);
      const float f1 = fmaxf(x1[j] + am.y, 0.f);
      s0 += f0; q0 = fmaf(f0, f0, q0);
      s1 += f1; q1 = fmaf(f1, f1, q1);
    }
  }
#pragma unroll
  for (int m = 1; m < 64; m <<= 1) {
    s0 += __shfl_xor(s0, m, 64); s1 += __shfl_xor(s1, m, 64);
    q0 += __shfl_xor(q0, m, 64); q1 += __shfl_xor(q1, m, 64);
  }
  if (lane == 0) {
    atomicAdd(&red[0], s0); atomicAdd(&red[1], s1);
    atomicAdd(&red[2], q0); atomicAdd(&red[3], q1);
  }
  __syncthreads();
  if (t == 0) {
    float4 v; v.x = red[0]; v.y = red[1]; v.z = red[2]; v.w = red[3];
    *(float4*)(ws + OFF_BNP + (size_t)(oc * 16 + b * 8 + tile) * 4) = v;
  }
}

// K4: redundant BN-final reduce (16 float4) per block, then out = f*scale + shift.
__global__ __launch_bounds__(256) void k4_out(const int* __restrict__ index,
    const float* __restrict__ gamma, const float* __restrict__ beta,
    const float* __restrict__ ws, float* __restrict__ out)
{
  __shared__ float am_s[128];
  __shared__ float4 tmp[16];
  __shared__ float sc_s[2], sh_s[2];
  const int blk = blockIdx.x, t = threadIdx.x;
  const int b = blk >> 8, oc = (blk >> 3) & 31, tile = blk & 7;
  const int o0 = oc * 2;
  if (t < 128) am_s[t] = ws[OFF_ADJM + (size_t)(b * 64 + (t >> 1)) * 64 + o0 + (t & 1)];
  if (t < 16) tmp[t] = *(const float4*)(ws + OFF_BNP + (size_t)(oc * 16 + t) * 4);
  if (t < 2) {   // same wave as tmp writers: per-wave LDS ordering suffices
    float s = 0.f, qq = 0.f;
#pragma unroll
    for (int i = 0; i < 16; ++i) {
      const float4 v = tmp[i];
      s  += (t == 0) ? v.x : v.y;
      qq += (t == 0) ? v.z : v.w;
    }
    const float mean = s * (1.f / 32768.f);
    const float var  = qq * (1.f / 32768.f) - mean * mean;
    const float sc = gamma[o0 + t] * rsqrtf(var + 1e-5f);
    sc_s[t] = sc;
    sh_s[t] = fmaf(-mean, sc, beta[o0 + t]);
  }
  __syncthreads();
  const int lane = t & 63, w = t >> 6;
  const unsigned short* xtu = (const unsigned short*)(ws + OFF_XT);
  const float c0 = sc_s[0], c1 = sc_s[1], h0 = sh_s[0], h1 = sh_s[1];
#pragma unroll
  for (int q = 0; q < 2; ++q) {
    const int px = tile * 2048 + (w * 2 + q) * 256 + lane * 4;
    const int4 kv = *(const int4*)(index + b * HW + px);
    const ushort4 u0 = *(const ushort4*)(xtu + (size_t)(b * 64 + o0    ) * HW + px);
    const ushort4 u1 = *(const ushort4*)(xtu + (size_t)(b * 64 + o0 + 1) * HW + px);
    const int kk[4] = {kv.x, kv.y, kv.z, kv.w};
    const float x0[4] = {bf2f(u0.x), bf2f(u0.y), bf2f(u0.z), bf2f(u0.w)};
    const float x1[4] = {bf2f(u1.x), bf2f(u1.y), bf2f(u1.z), bf2f(u1.w)};
    float4 o4a, o4b;
    float* oa = (float*)&o4a; float* ob = (float*)&o4b;
#pragma unroll
    for (int j = 0; j < 4; ++j) {
      const float2 am = *(const float2*)&am_s[kk[j] * 2];
      oa[j] = fmaf(fmaxf(x0[j] + am.x, 0.f), c0, h0);
      ob[j] = fmaf(fmaxf(x1[j] + am.y, 0.f), c1, h1);
    }
    *(float4*)(out + (size_t)(b * 64 + o0    ) * HW + px) = o4a;
    *(float4*)(out + (size_t)(b * 64 + o0 + 1) * HW + px) = o4b;
  }
}

extern "C" void kernel_launch(void* const* d_in, const int* in_sizes, int n_in,
                              void* d_out, int out_size, void* d_ws, size_t ws_size,
                              hipStream_t stream) {
  const float* x     = (const float*)d_in[0];
  const int*   index = (const int*)d_in[1];
  const float* Wft   = (const float*)d_in[2];
  const float* Wm    = (const float*)d_in[3];
  const float* gamma = (const float*)d_in[4];
  const float* beta  = (const float*)d_in[5];
  float* ws  = (float*)d_ws;
  float* out = (float*)d_out;

  k1_xt_bins_inv<<<513, 256, 0, stream>>>(x, index, Wft, Wm, ws);
  k15_means_diag<<<128, 1024, 0, stream>>>(ws);
  k2_adj<<<16, 256, 0, stream>>>(ws);
  k3_bnstats<<<512, 256, 0, stream>>>(index, ws);
  k4_out<<<512, 256, 0, stream>>>(index, gamma, beta, ws, out);
}

// Round 6
// 143.373 us; speedup vs baseline: 2.0788x; 2.0788x over previous
//
#include <hip/hip_runtime.h>
#include <hip/hip_bf16.h>

// Problem constants
#define CIN   128
#define COUT  64
#define HW    16384   // 128*128

typedef __hip_bfloat16 bf16;

// Workspace layout (float offsets) — total 2,152,576 floats = 8.6 MB
#define OFF_XT    0u          // bf16[2][64][16384]  xt            (1048576 f-equiv)
#define OFF_PS    1048576u    // bf16[512 blk][64 k][64 o] partial bin sums (1048576 f-equiv)
#define OFF_PC    2097152u    // f32 [2][64][256]    partial bin counts
#define OFF_MEANS 2129920u    // f32 [2][64][64]
#define OFF_DIAG  2138112u    // f32 [2][64]         m^T C^-1 m
#define OFF_INV   2138240u    // f32 [64][64]        inv(cov) (symmetric)
#define OFF_ADJM  2142336u    // f32 [2][64][64]     adj @ means
#define OFF_BNP   2150528u    // f32 [32 oc][16 b*tile] float4 {s0,s1,ss0,ss1}

__device__ __forceinline__ unsigned short f2bfu(float f) {
  union { bf16 h; unsigned short u; } cv; cv.h = __float2bfloat16(f); return cv.u;
}
__device__ __forceinline__ float bf2f(unsigned short u) {
  union { unsigned int i; float f; } cv; cv.i = ((unsigned int)u) << 16; return cv.f;
}

// K1: xt = einsum('bchw,co->bohw') (bf16 out) + per-block bin partials; block 512 = inv(Wm Wm^T).
// LDS-staged GEMM: block = 64 px x 64 o x 128 c. x tile 32KB + Wft 32KB = 64KB -> 2 blocks/CU.
// Inverse block: cov tile in regs (thread = 4x4), then PARALLEL Gauss-Jordan:
// per step publish pivot row/col segments to dbuf LDS strips, 1 barrier, 16 reg FMAs.
// (R5 lesson: single-wave fully-unrolled GJ = 36KB straight-line code + spill roulette = 195us.)
__global__ __launch_bounds__(256, 2) void k1_xt_bins_inv(
    const float* __restrict__ x, const int* __restrict__ index,
    const float* __restrict__ Wft, const float* __restrict__ Wm,
    float* __restrict__ ws)
{
  __shared__ __align__(16) float smem[16384];   // 64 KB
  const int blk = blockIdx.x, tid = threadIdx.x;
  if (blk < 512) {
    float* xl = smem;          // [128 c][64 px]
    float* wl = smem + 8192;   // [128 c][64 o]
    const int b = blk >> 8, ps = blk & 255;
    // ---- stage x slab (64 px x 128 c) and all of Wft, bulk-coalesced
    const float* xg = x + (size_t)b * CIN * HW + ps * 64;
#pragma unroll
    for (int j = 0; j < 8; ++j) {
      const int fj = j * 256 + tid;            // float4 id
      const int c = fj >> 4, q4 = (fj & 15) * 4;
      *(float4*)&xl[c * 64 + q4] = *(const float4*)(xg + (size_t)c * HW + q4);
      *(float4*)&wl[c * 64 + q4] = *(const float4*)(Wft + c * 64 + q4);
    }
    __syncthreads();
    // ---- register-tiled compute
    const int px_grp = tid & 15, o_grp = tid >> 4;
    const int px = ps * 64 + px_grp * 4, o0 = o_grp * 4;
    float acc[16];
#pragma unroll
    for (int j = 0; j < 16; ++j) acc[j] = 0.f;
#pragma unroll 8
    for (int c = 0; c < 128; ++c) {
      const float4 xv = *(const float4*)&xl[c * 64 + px_grp * 4];
      const float4 wv = *(const float4*)&wl[c * 64 + o0];
      acc[ 0]=fmaf(xv.x,wv.x,acc[ 0]); acc[ 1]=fmaf(xv.y,wv.x,acc[ 1]);
      acc[ 2]=fmaf(xv.z,wv.x,acc[ 2]); acc[ 3]=fmaf(xv.w,wv.x,acc[ 3]);
      acc[ 4]=fmaf(xv.x,wv.y,acc[ 4]); acc[ 5]=fmaf(xv.y,wv.y,acc[ 5]);
      acc[ 6]=fmaf(xv.z,wv.y,acc[ 6]); acc[ 7]=fmaf(xv.w,wv.y,acc[ 7]);
      acc[ 8]=fmaf(xv.x,wv.z,acc[ 8]); acc[ 9]=fmaf(xv.y,wv.z,acc[ 9]);
      acc[10]=fmaf(xv.z,wv.z,acc[10]); acc[11]=fmaf(xv.w,wv.z,acc[11]);
      acc[12]=fmaf(xv.x,wv.w,acc[12]); acc[13]=fmaf(xv.y,wv.w,acc[13]);
      acc[14]=fmaf(xv.z,wv.w,acc[14]); acc[15]=fmaf(xv.w,wv.w,acc[15]);
    }
    // ---- write xt (bf16)
    unsigned short* xtu = (unsigned short*)(ws + OFF_XT);
#pragma unroll
    for (int oj = 0; oj < 4; ++oj) {
      ushort4 u;
      u.x = f2bfu(acc[oj*4+0]); u.y = f2bfu(acc[oj*4+1]);
      u.z = f2bfu(acc[oj*4+2]); u.w = f2bfu(acc[oj*4+3]);
      *(ushort4*)(xtu + (size_t)(b * 64 + o0 + oj) * HW + px) = u;
    }
    // ---- bin partials (reuse LDS after compute done)
    const int4 kv = *(const int4*)(index + b * HW + px);
    const int kk[4] = {kv.x, kv.y, kv.z, kv.w};
    __syncthreads();                       // all LDS compute reads done
    float* bins = smem;                    // [64 k][68] padded
    float* cnt  = smem + 64 * 68;          // [64]
    for (int i = tid; i < 64 * 68 + 64; i += 256) smem[i] = 0.f;
    __syncthreads();
#pragma unroll
    for (int pj = 0; pj < 4; ++pj) {
      const int kb = kk[pj] * 68 + o0;
      atomicAdd(&bins[kb    ], acc[ 0 + pj]);
      atomicAdd(&bins[kb + 1], acc[ 4 + pj]);
      atomicAdd(&bins[kb + 2], acc[ 8 + pj]);
      atomicAdd(&bins[kb + 3], acc[12 + pj]);
    }
    if (o_grp == 0) {   // exactly one thread per px (R3 lesson: guard the o replication)
#pragma unroll
      for (int pj = 0; pj < 4; ++pj) atomicAdd(&cnt[kk[pj]], 1.f);
    }
    __syncthreads();
    // ---- dump partials as bf16: [64 k][64 o]
    unsigned short* pb = (unsigned short*)(ws + OFF_PS) + (size_t)blk * 4096;
    {
      const int k = tid >> 2, ob = (tid & 3) * 16;
#pragma unroll
      for (int q = 0; q < 4; ++q) {
        const float4 v = *(const float4*)&bins[k * 68 + ob + q * 4];
        ushort4 u;
        u.x = f2bfu(v.x); u.y = f2bfu(v.y); u.z = f2bfu(v.z); u.w = f2bfu(v.w);
        *(ushort4*)(pb + k * 64 + ob + q * 4) = u;
      }
    }
    if (tid < 64) ws[OFF_PC + (size_t)(b * 64 + tid) * 256 + ps] = cnt[tid];
  } else {
    // ---- inverse block: cov = Wm Wm^T in regs (thread = rows i0..i0+3 x cols j0..j0+3),
    //      then parallel in-place Gauss-Jordan on the register tiles (SPD, no pivoting).
    float* wm = smem;             // [64][68]
    float* pr = smem + 8192;      // [2][64] pivot-row double buffer
    float* pc = smem + 8320;      // [2][64] pivot-col double buffer
    for (int e = tid; e < 4096; e += 256) wm[(e >> 6) * 68 + (e & 63)] = Wm[e];
    __syncthreads();
    const int ig = tid >> 4, jg = tid & 15;
    const int i0 = ig << 2, j0 = jg << 2;
    float c4[16];
#pragma unroll
    for (int q = 0; q < 16; ++q) c4[q] = 0.f;
    for (int cq = 0; cq < 64; cq += 4) {
      float4 a[4], bb[4];
#pragma unroll
      for (int ii = 0; ii < 4; ++ii) a[ii]  = *(const float4*)&wm[(i0+ii)*68 + cq];
#pragma unroll
      for (int jj = 0; jj < 4; ++jj) bb[jj] = *(const float4*)&wm[(j0+jj)*68 + cq];
#pragma unroll
      for (int ii = 0; ii < 4; ++ii)
#pragma unroll
        for (int jj = 0; jj < 4; ++jj)
          c4[ii*4+jj] = fmaf(a[ii].x, bb[jj].x, fmaf(a[ii].y, bb[jj].y,
                        fmaf(a[ii].z, bb[jj].z, fmaf(a[ii].w, bb[jj].w, c4[ii*4+jj]))));
    }
    __syncthreads();   // wm reads done; pr/pc strips live elsewhere anyway
    __builtin_amdgcn_s_setprio(3);   // tiny critical block: win arbitration vs einsum waves
    int buf = 0;
    for (int k = 0; k < 64; ++k) {
      const int kg = k >> 2, kr = k & 3;
      if (ig == kg) {               // I own 4 cols of row k -> publish
        pr[buf * 64 + j0 + 0] = c4[kr * 4 + 0];
        pr[buf * 64 + j0 + 1] = c4[kr * 4 + 1];
        pr[buf * 64 + j0 + 2] = c4[kr * 4 + 2];
        pr[buf * 64 + j0 + 3] = c4[kr * 4 + 3];
      }
      if (jg == kg) {               // I own 4 rows of col k -> publish
        pc[buf * 64 + i0 + 0] = c4[0 * 4 + kr];
        pc[buf * 64 + i0 + 1] = c4[1 * 4 + kr];
        pc[buf * 64 + i0 + 2] = c4[2 * 4 + kr];
        pc[buf * 64 + i0 + 3] = c4[3 * 4 + kr];
      }
      __syncthreads();              // single barrier per step (dbuf makes it safe)
      const float rp = 1.0f / pr[buf * 64 + k];
      float s[4], ai[4];
#pragma unroll
      for (int jj = 0; jj < 4; ++jj) s[jj] = pr[buf * 64 + j0 + jj];
#pragma unroll
      for (int ii = 0; ii < 4; ++ii)
        ai[ii] = (i0 + ii == k) ? (rp - 1.0f) : (-pc[buf * 64 + i0 + ii] * rp);
#pragma unroll
      for (int ii = 0; ii < 4; ++ii)
#pragma unroll
        for (int jj = 0; jj < 4; ++jj)
          c4[ii*4+jj] = fmaf(ai[ii], s[jj], c4[ii*4+jj]);
      if (jg == kg) {               // column-k fix (I own it)
#pragma unroll
        for (int ii = 0; ii < 4; ++ii)
          c4[ii*4+kr] = (i0 + ii == k) ? rp : ai[ii];
      }
      buf ^= 1;
    }
    __builtin_amdgcn_s_setprio(0);
#pragma unroll
    for (int ii = 0; ii < 4; ++ii)
#pragma unroll
      for (int jj = 0; jj < 4; ++jj)
        ws[OFF_INV + (size_t)(i0 + ii) * 64 + j0 + jj] = c4[ii*4+jj];
  }
}

// K1.5: reduce bin partials -> means; diag[b][k] = m^T C^-1 m. 128 blocks x 1024 thr.
__global__ __launch_bounds__(1024) void k15_means_diag(float* __restrict__ ws)
{
  __shared__ float red[1024];
  __shared__ float lds_c[4];
  __shared__ float lds_m[64];
  const int blk = blockIdx.x, t = threadIdx.x;
  const int b = blk >> 6, k = blk & 63;
  const int o = t & 63, chunk = t >> 6;
  const unsigned short* psu = (const unsigned short*)(ws + OFF_PS);
  float s = 0.f;
#pragma unroll
  for (int i = 0; i < 16; ++i) {
    const int slab = chunk * 16 + i;
    s += bf2f(psu[(size_t)(b * 256 + slab) * 4096 + k * 64 + o]);
  }
  red[chunk * 64 + o] = s;
  float cv = 0.f;
  if (t < 256) cv = ws[OFF_PC + (size_t)(b * 64 + k) * 256 + t];
#pragma unroll
  for (int m = 32; m; m >>= 1) cv += __shfl_xor(cv, m, 64);
  if (t < 256 && (t & 63) == 0) lds_c[t >> 6] = cv;
  __syncthreads();
  if (t < 64) {
    float m_raw = 0.f;
#pragma unroll
    for (int ch = 0; ch < 16; ++ch) m_raw += red[ch * 64 + o];
    const float cnt = lds_c[0] + lds_c[1] + lds_c[2] + lds_c[3];
    const float denom = cnt + ((cnt == 0.f) ? 1.f : 0.f);
    const float m = m_raw / denom;
    ws[OFF_MEANS + (size_t)(b * 64 + k) * 64 + o] = m;
    lds_m[o] = m;
    float inner = 0.f;  // inv symmetric -> coalesced column reads
#pragma unroll 8
    for (int d = 0; d < 64; ++d) inner = fmaf(ws[OFF_INV + d * 64 + o], lds_m[d], inner);
    float p = m * inner;
#pragma unroll
    for (int mm = 32; mm; mm >>= 1) p += __shfl_xor(p, mm, 64);
    if (o == 0) ws[OFF_DIAG + b * 64 + k] = p;
  }
}

// K2: T = means@inv ; q = diag_i+diag_j-2*T_i.m_j ; adj = exp(-sqrt(max(q,1e-12))) ; AM = adj@means
__global__ __launch_bounds__(256) void k2_adj(float* __restrict__ ws)
{
  __shared__ __align__(16) float means_s[64 * 68];
  __shared__ __align__(16) float inv_s[64 * 68];
  __shared__ __align__(16) float T_s[8 * 68];
  __shared__ __align__(16) float adj_s[8 * 68];
  __shared__ float diag_s[64];
  const int b = blockIdx.x >> 3;
  const int i0 = (blockIdx.x & 7) << 3;
  const int t = threadIdx.x;
  const float* mg = ws + OFF_MEANS + b * 4096;
  for (int e = t; e < 4096; e += 256) means_s[(e >> 6) * 68 + (e & 63)] = mg[e];
  const float* ig = ws + OFF_INV;
  for (int e = t; e < 4096; e += 256) inv_s[(e >> 6) * 68 + (e & 63)] = ig[e];
  if (t < 64) diag_s[t] = ws[OFF_DIAG + b * 64 + t];
  __syncthreads();
  if (t < 128) {
    const int i = t >> 4, d0 = (t & 15) << 2;
    float4 acc = {0.f, 0.f, 0.f, 0.f};
    for (int c = 0; c < 64; ++c) {
      const float mv = means_s[(i0 + i) * 68 + c];
      const float4 iv = *(const float4*)&inv_s[c * 68 + d0];
      acc.x = fmaf(mv, iv.x, acc.x); acc.y = fmaf(mv, iv.y, acc.y);
      acc.z = fmaf(mv, iv.z, acc.z); acc.w = fmaf(mv, iv.w, acc.w);
    }
    *(float4*)&T_s[i * 68 + d0] = acc;
  }
  __syncthreads();
  {
    const int i = t >> 5, jb = t & 31;
#pragma unroll
    for (int jj = 0; jj < 2; ++jj) {
      const int j = jb + (jj << 5);
      float4 p4 = {0.f, 0.f, 0.f, 0.f};
      for (int dq = 0; dq < 64; dq += 4) {
        const float4 tv = *(const float4*)&T_s[i * 68 + dq];
        const float4 mv = *(const float4*)&means_s[j * 68 + dq];
        p4.x = fmaf(tv.x, mv.x, p4.x); p4.y = fmaf(tv.y, mv.y, p4.y);
        p4.z = fmaf(tv.z, mv.z, p4.z); p4.w = fmaf(tv.w, mv.w, p4.w);
      }
      const float p = (p4.x + p4.y) + (p4.z + p4.w);
      const float q = diag_s[i0 + i] + diag_s[j] - 2.f * p;
      adj_s[i * 68 + j] = __expf(-sqrtf(fmaxf(q, 1e-12f)));
    }
  }
  __syncthreads();
  if (t < 128) {
    const int i = t >> 4, oq = (t & 15) << 2;
    float4 am = {0.f, 0.f, 0.f, 0.f};
    for (int j = 0; j < 64; ++j) {
      const float av = adj_s[i * 68 + j];
      const float4 mv = *(const float4*)&means_s[j * 68 + oq];
      am.x = fmaf(av, mv.x, am.x); am.y = fmaf(av, mv.y, am.y);
      am.z = fmaf(av, mv.z, am.z); am.w = fmaf(av, mv.w, am.w);
    }
    *(float4*)(ws + OFF_ADJM + (size_t)(b * 64 + i0 + i) * 64 + oq) = am;
  }
}

// K3: BN partial stats of f = relu(xt + adj_means[idx]). 512 blocks: (b, o-pair oc, 2048-px tile).
__global__ __launch_bounds__(256) void k3_bnstats(const int* __restrict__ index,
                                                  float* __restrict__ ws)
{
  __shared__ float am_s[128];   // [64 k][2 o]
  __shared__ float red[4];
  const int blk = blockIdx.x, t = threadIdx.x;
  const int b = blk >> 8, oc = (blk >> 3) & 31, tile = blk & 7;
  const int o0 = oc * 2;
  if (t < 128) am_s[t] = ws[OFF_ADJM + (size_t)(b * 64 + (t >> 1)) * 64 + o0 + (t & 1)];
  if (t < 4) red[t] = 0.f;
  __syncthreads();
  const int lane = t & 63, w = t >> 6;
  const unsigned short* xtu = (const unsigned short*)(ws + OFF_XT);
  float s0 = 0.f, s1 = 0.f, q0 = 0.f, q1 = 0.f;
#pragma unroll
  for (int q = 0; q < 2; ++q) {
    const int px = tile * 2048 + (w * 2 + q) * 256 + lane * 4;
    const int4 kv = *(const int4*)(index + b * HW + px);
    const ushort4 u0 = *(const ushort4*)(xtu + (size_t)(b * 64 + o0    ) * HW + px);
    const ushort4 u1 = *(const ushort4*)(xtu + (size_t)(b * 64 + o0 + 1) * HW + px);
    const int kk[4] = {kv.x, kv.y, kv.z, kv.w};
    const float x0[4] = {bf2f(u0.x), bf2f(u0.y), bf2f(u0.z), bf2f(u0.w)};
    const float x1[4] = {bf2f(u1.x), bf2f(u1.y), bf2f(u1.z), bf2f(u1.w)};
#pragma unroll
    for (int j = 0; j < 4; ++j) {
      const float2 am = *(const float2*)&am_s[kk[j] * 2];
      const float f0 = fmaxf(x0[j] + am.x, 0.f);
      const float f1 = fmaxf(x1[j] + am.y, 0.f);
      s0 += f0; q0 = fmaf(f0, f0, q0);
      s1 += f1; q1 = fmaf(f1, f1, q1);
    }
  }
#pragma unroll
  for (int m = 1; m < 64; m <<= 1) {
    s0 += __shfl_xor(s0, m, 64); s1 += __shfl_xor(s1, m, 64);
    q0 += __shfl_xor(q0, m, 64); q1 += __shfl_xor(q1, m, 64);
  }
  if (lane == 0) {
    atomicAdd(&red[0], s0); atomicAdd(&red[1], s1);
    atomicAdd(&red[2], q0); atomicAdd(&red[3], q1);
  }
  __syncthreads();
  if (t == 0) {
    float4 v; v.x = red[0]; v.y = red[1]; v.z = red[2]; v.w = red[3];
    *(float4*)(ws + OFF_BNP + (size_t)(oc * 16 + b * 8 + tile) * 4) = v;
  }
}

// K4: redundant BN-final reduce (16 float4) per block, then out = f*scale + shift.
__global__ __launch_bounds__(256) void k4_out(const int* __restrict__ index,
    const float* __restrict__ gamma, const float* __restrict__ beta,
    const float* __restrict__ ws, float* __restrict__ out)
{
  __shared__ float am_s[128];
  __shared__ float4 tmp[16];
  __shared__ float sc_s[2], sh_s[2];
  const int blk = blockIdx.x, t = threadIdx.x;
  const int b = blk >> 8, oc = (blk >> 3) & 31, tile = blk & 7;
  const int o0 = oc * 2;
  if (t < 128) am_s[t] = ws[OFF_ADJM + (size_t)(b * 64 + (t >> 1)) * 64 + o0 + (t & 1)];
  if (t < 16) tmp[t] = *(const float4*)(ws + OFF_BNP + (size_t)(oc * 16 + t) * 4);
  if (t < 2) {   // same wave as tmp writers: per-wave LDS ordering suffices
    float s = 0.f, qq = 0.f;
#pragma unroll
    for (int i = 0; i < 16; ++i) {
      const float4 v = tmp[i];
      s  += (t == 0) ? v.x : v.y;
      qq += (t == 0) ? v.z : v.w;
    }
    const float mean = s * (1.f / 32768.f);
    const float var  = qq * (1.f / 32768.f) - mean * mean;
    const float sc = gamma[o0 + t] * rsqrtf(var + 1e-5f);
    sc_s[t] = sc;
    sh_s[t] = fmaf(-mean, sc, beta[o0 + t]);
  }
  __syncthreads();
  const int lane = t & 63, w = t >> 6;
  const unsigned short* xtu = (const unsigned short*)(ws + OFF_XT);
  const float c0 = sc_s[0], c1 = sc_s[1], h0 = sh_s[0], h1 = sh_s[1];
#pragma unroll
  for (int q = 0; q < 2; ++q) {
    const int px = tile * 2048 + (w * 2 + q) * 256 + lane * 4;
    const int4 kv = *(const int4*)(index + b * HW + px);
    const ushort4 u0 = *(const ushort4*)(xtu + (size_t)(b * 64 + o0    ) * HW + px);
    const ushort4 u1 = *(const ushort4*)(xtu + (size_t)(b * 64 + o0 + 1) * HW + px);
    const int kk[4] = {kv.x, kv.y, kv.z, kv.w};
    const float x0[4] = {bf2f(u0.x), bf2f(u0.y), bf2f(u0.z), bf2f(u0.w)};
    const float x1[4] = {bf2f(u1.x), bf2f(u1.y), bf2f(u1.z), bf2f(u1.w)};
    float4 o4a, o4b;
    float* oa = (float*)&o4a; float* ob = (float*)&o4b;
#pragma unroll
    for (int j = 0; j < 4; ++j) {
      const float2 am = *(const float2*)&am_s[kk[j] * 2];
      oa[j] = fmaf(fmaxf(x0[j] + am.x, 0.f), c0, h0);
      ob[j] = fmaf(fmaxf(x1[j] + am.y, 0.f), c1, h1);
    }
    *(float4*)(out + (size_t)(b * 64 + o0    ) * HW + px) = o4a;
    *(float4*)(out + (size_t)(b * 64 + o0 + 1) * HW + px) = o4b;
  }
}

extern "C" void kernel_launch(void* const* d_in, const int* in_sizes, int n_in,
                              void* d_out, int out_size, void* d_ws, size_t ws_size,
                              hipStream_t stream) {
  const float* x     = (const float*)d_in[0];
  const int*   index = (const int*)d_in[1];
  const float* Wft   = (const float*)d_in[2];
  const float* Wm    = (const float*)d_in[3];
  const float* gamma = (const float*)d_in[4];
  const float* beta  = (const float*)d_in[5];
  float* ws  = (float*)d_ws;
  float* out = (float*)d_out;

  k1_xt_bins_inv<<<513, 256, 0, stream>>>(x, index, Wft, Wm, ws);
  k15_means_diag<<<128, 1024, 0, stream>>>(ws);
  k2_adj<<<16, 256, 0, stream>>>(ws);
  k3_bnstats<<<512, 256, 0, stream>>>(index, ws);
  k4_out<<<512, 256, 0, stream>>>(index, gamma, beta, ws, out);
}

// Round 7
// 129.751 us; speedup vs baseline: 2.2970x; 1.1050x over previous
//
#include <hip/hip_runtime.h>
#include <hip/hip_bf16.h>

// Problem constants
#define CIN   128
#define COUT  64
#define HW    16384   // 128*128

typedef __hip_bfloat16 bf16;

// Workspace layout (float offsets) — total 2,152,576 floats = 8.6 MB
#define OFF_XT    0u          // bf16[2][64][16384]  xt            (1048576 f-equiv)
#define OFF_PS    1048576u    // bf16[512 blk][64 k][64 o] partial bin sums (1048576 f-equiv)
#define OFF_PC    2097152u    // f32 [2][64][256]    partial bin counts
#define OFF_MEANS 2129920u    // f32 [2][64][64]
#define OFF_DIAG  2138112u    // f32 [2][64]         m^T C^-1 m
#define OFF_INV   2138240u    // f32 [64][64]        inv(cov) (symmetric)
#define OFF_ADJM  2142336u    // f32 [2][64][64]     adj @ means
#define OFF_BNP   2150528u    // f32 [32 oc][16 b*tile] float4 {s0,s1,ss0,ss1}

__device__ __forceinline__ unsigned short f2bfu(float f) {
  union { bf16 h; unsigned short u; } cv; cv.h = __float2bfloat16(f); return cv.u;
}
__device__ __forceinline__ float bf2f(unsigned short u) {
  union { unsigned int i; float f; } cv; cv.i = ((unsigned int)u) << 16; return cv.f;
}

// K1: xt = einsum('bchw,co->bohw') (bf16 out) + per-block bin partials; block 0 = inv(Wm Wm^T).
// (R6 lessons: inv must be block 0 — as block 512 it was the 513th block, started after the
// einsum drained and ran on a near-idle GPU; and the GJ step loop must NOT unroll — kg/kr
// const-fold makes the compiler emit 64 specialized bodies = I$ thrash, the R5 disease.)
__global__ __launch_bounds__(256, 2) void k1_xt_bins_inv(
    const float* __restrict__ x, const int* __restrict__ index,
    const float* __restrict__ Wft, const float* __restrict__ Wm,
    float* __restrict__ ws)
{
  __shared__ __align__(16) float smem[16384];   // 64 KB
  const int blk = blockIdx.x, tid = threadIdx.x;
  if (blk != 0) {
    float* xl = smem;          // [128 c][64 px]
    float* wl = smem + 8192;   // [128 c][64 o]
    const int eb = blk - 1;
    const int b = eb >> 8, ps = eb & 255;
    // ---- stage x slab (64 px x 128 c) and all of Wft, bulk-coalesced
    const float* xg = x + (size_t)b * CIN * HW + ps * 64;
#pragma unroll
    for (int j = 0; j < 8; ++j) {
      const int fj = j * 256 + tid;            // float4 id
      const int c = fj >> 4, q4 = (fj & 15) * 4;
      *(float4*)&xl[c * 64 + q4] = *(const float4*)(xg + (size_t)c * HW + q4);
      *(float4*)&wl[c * 64 + q4] = *(const float4*)(Wft + c * 64 + q4);
    }
    __syncthreads();
    // ---- register-tiled compute: thread = 4px x 4o
    const int px_grp = tid & 15, o_grp = tid >> 4;
    const int px = ps * 64 + px_grp * 4, o0 = o_grp * 4;
    float acc[16];
#pragma unroll
    for (int j = 0; j < 16; ++j) acc[j] = 0.f;
#pragma unroll 8
    for (int c = 0; c < 128; ++c) {
      const float4 xv = *(const float4*)&xl[c * 64 + px_grp * 4];
      const float4 wv = *(const float4*)&wl[c * 64 + o0];
      acc[ 0]=fmaf(xv.x,wv.x,acc[ 0]); acc[ 1]=fmaf(xv.y,wv.x,acc[ 1]);
      acc[ 2]=fmaf(xv.z,wv.x,acc[ 2]); acc[ 3]=fmaf(xv.w,wv.x,acc[ 3]);
      acc[ 4]=fmaf(xv.x,wv.y,acc[ 4]); acc[ 5]=fmaf(xv.y,wv.y,acc[ 5]);
      acc[ 6]=fmaf(xv.z,wv.y,acc[ 6]); acc[ 7]=fmaf(xv.w,wv.y,acc[ 7]);
      acc[ 8]=fmaf(xv.x,wv.z,acc[ 8]); acc[ 9]=fmaf(xv.y,wv.z,acc[ 9]);
      acc[10]=fmaf(xv.z,wv.z,acc[10]); acc[11]=fmaf(xv.w,wv.z,acc[11]);
      acc[12]=fmaf(xv.x,wv.w,acc[12]); acc[13]=fmaf(xv.y,wv.w,acc[13]);
      acc[14]=fmaf(xv.z,wv.w,acc[14]); acc[15]=fmaf(xv.w,wv.w,acc[15]);
    }
    // ---- write xt (bf16)
    unsigned short* xtu = (unsigned short*)(ws + OFF_XT);
#pragma unroll
    for (int oj = 0; oj < 4; ++oj) {
      ushort4 u;
      u.x = f2bfu(acc[oj*4+0]); u.y = f2bfu(acc[oj*4+1]);
      u.z = f2bfu(acc[oj*4+2]); u.w = f2bfu(acc[oj*4+3]);
      *(ushort4*)(xtu + (size_t)(b * 64 + o0 + oj) * HW + px) = u;
    }
    // ---- bin partials (reuse LDS after compute done)
    const int4 kv = *(const int4*)(index + b * HW + px);
    const int kk[4] = {kv.x, kv.y, kv.z, kv.w};
    __syncthreads();                       // all LDS compute reads done
    float* bins = smem;                    // [64 k][68] padded
    float* cnt  = smem + 64 * 68;          // [64]
    for (int i = tid; i < 64 * 68 + 64; i += 256) smem[i] = 0.f;
    __syncthreads();
#pragma unroll
    for (int pj = 0; pj < 4; ++pj) {
      const int kb = kk[pj] * 68 + o0;
      atomicAdd(&bins[kb    ], acc[ 0 + pj]);
      atomicAdd(&bins[kb + 1], acc[ 4 + pj]);
      atomicAdd(&bins[kb + 2], acc[ 8 + pj]);
      atomicAdd(&bins[kb + 3], acc[12 + pj]);
    }
    if (o_grp == 0) {   // exactly one thread per px (R3 lesson: guard the o replication)
#pragma unroll
      for (int pj = 0; pj < 4; ++pj) atomicAdd(&cnt[kk[pj]], 1.f);
    }
    __syncthreads();
    // ---- dump partials as bf16: [64 k][64 o]
    unsigned short* pb = (unsigned short*)(ws + OFF_PS) + (size_t)eb * 4096;
    {
      const int k = tid >> 2, ob = (tid & 3) * 16;
#pragma unroll
      for (int q = 0; q < 4; ++q) {
        const float4 v = *(const float4*)&bins[k * 68 + ob + q * 4];
        ushort4 u;
        u.x = f2bfu(v.x); u.y = f2bfu(v.y); u.z = f2bfu(v.z); u.w = f2bfu(v.w);
        *(ushort4*)(pb + k * 64 + ob + q * 4) = u;
      }
    }
    if (tid < 64) ws[OFF_PC + (size_t)(b * 64 + tid) * 256 + ps] = cnt[tid];
  } else {
    // ---- inverse block (block 0, starts at t=0, overlapped with einsum blocks):
    //      cov = Wm Wm^T in regs (thread = 4x4 tile), parallel in-place Gauss-Jordan.
    float* wm = smem;             // [64][68]
    float* pr = smem + 8192;      // [2][64] pivot-row double buffer
    float* pc = smem + 8320;      // [2][64] pivot-col double buffer
    for (int e = tid; e < 4096; e += 256) wm[(e >> 6) * 68 + (e & 63)] = Wm[e];
    __syncthreads();
    const int ig = tid >> 4, jg = tid & 15;
    const int i0 = ig << 2, j0 = jg << 2;
    float c4[16];
#pragma unroll
    for (int q = 0; q < 16; ++q) c4[q] = 0.f;
    for (int cq = 0; cq < 64; cq += 4) {
      float4 a[4], bb[4];
#pragma unroll
      for (int ii = 0; ii < 4; ++ii) a[ii]  = *(const float4*)&wm[(i0+ii)*68 + cq];
#pragma unroll
      for (int jj = 0; jj < 4; ++jj) bb[jj] = *(const float4*)&wm[(j0+jj)*68 + cq];
#pragma unroll
      for (int ii = 0; ii < 4; ++ii)
#pragma unroll
        for (int jj = 0; jj < 4; ++jj)
          c4[ii*4+jj] = fmaf(a[ii].x, bb[jj].x, fmaf(a[ii].y, bb[jj].y,
                        fmaf(a[ii].z, bb[jj].z, fmaf(a[ii].w, bb[jj].w, c4[ii*4+jj]))));
    }
    __syncthreads();   // wm reads done
    __builtin_amdgcn_s_setprio(3);   // win arbitration vs co-resident einsum waves
    int buf = 0;
#pragma unroll 1   // MUST stay rolled: unrolled = 64 specialized bodies = I$ thrash (R5/R6)
    for (int k = 0; k < 64; ++k) {
      const int kg = k >> 2, kr = k & 3;
      if (ig == kg) {               // I own 4 cols of row k -> publish
        pr[buf * 64 + j0 + 0] = c4[kr * 4 + 0];
        pr[buf * 64 + j0 + 1] = c4[kr * 4 + 1];
        pr[buf * 64 + j0 + 2] = c4[kr * 4 + 2];
        pr[buf * 64 + j0 + 3] = c4[kr * 4 + 3];
      }
      if (jg == kg) {               // I own 4 rows of col k -> publish
        pc[buf * 64 + i0 + 0] = c4[0 * 4 + kr];
        pc[buf * 64 + i0 + 1] = c4[1 * 4 + kr];
        pc[buf * 64 + i0 + 2] = c4[2 * 4 + kr];
        pc[buf * 64 + i0 + 3] = c4[3 * 4 + kr];
      }
      __syncthreads();              // single barrier per step (dbuf makes it safe)
      const float rp = __builtin_amdgcn_rcpf(pr[buf * 64 + k]);
      float s[4], ai[4];
#pragma unroll
      for (int jj = 0; jj < 4; ++jj) s[jj] = pr[buf * 64 + j0 + jj];
#pragma unroll
      for (int ii = 0; ii < 4; ++ii)
        ai[ii] = (i0 + ii == k) ? (rp - 1.0f) : (-pc[buf * 64 + i0 + ii] * rp);
#pragma unroll
      for (int ii = 0; ii < 4; ++ii)
#pragma unroll
        for (int jj = 0; jj < 4; ++jj)
          c4[ii*4+jj] = fmaf(ai[ii], s[jj], c4[ii*4+jj]);
      if (jg == kg) {               // column-k fix (I own it)
#pragma unroll
        for (int ii = 0; ii < 4; ++ii)
          c4[ii*4+kr] = (i0 + ii == k) ? rp : ai[ii];
      }
      buf ^= 1;
    }
    __builtin_amdgcn_s_setprio(0);
#pragma unroll
    for (int ii = 0; ii < 4; ++ii)
#pragma unroll
      for (int jj = 0; jj < 4; ++jj)
        ws[OFF_INV + (size_t)(i0 + ii) * 64 + j0 + jj] = c4[ii*4+jj];
  }
}

// K1.5: reduce bin partials -> means; diag[b][k] = m^T C^-1 m. 128 blocks x 1024 thr.
__global__ __launch_bounds__(1024) void k15_means_diag(float* __restrict__ ws)
{
  __shared__ float red[1024];
  __shared__ float lds_c[4];
  __shared__ float lds_m[64];
  const int blk = blockIdx.x, t = threadIdx.x;
  const int b = blk >> 6, k = blk & 63;
  const int o = t & 63, chunk = t >> 6;
  const unsigned short* psu = (const unsigned short*)(ws + OFF_PS);
  float s = 0.f;
#pragma unroll
  for (int i = 0; i < 16; ++i) {
    const int slab = chunk * 16 + i;
    s += bf2f(psu[(size_t)(b * 256 + slab) * 4096 + k * 64 + o]);
  }
  red[chunk * 64 + o] = s;
  float cv = 0.f;
  if (t < 256) cv = ws[OFF_PC + (size_t)(b * 64 + k) * 256 + t];
#pragma unroll
  for (int m = 32; m; m >>= 1) cv += __shfl_xor(cv, m, 64);
  if (t < 256 && (t & 63) == 0) lds_c[t >> 6] = cv;
  __syncthreads();
  if (t < 64) {
    float m_raw = 0.f;
#pragma unroll
    for (int ch = 0; ch < 16; ++ch) m_raw += red[ch * 64 + o];
    const float cnt = lds_c[0] + lds_c[1] + lds_c[2] + lds_c[3];
    const float denom = cnt + ((cnt == 0.f) ? 1.f : 0.f);
    const float m = m_raw / denom;
    ws[OFF_MEANS + (size_t)(b * 64 + k) * 64 + o] = m;
    lds_m[o] = m;
    float inner = 0.f;  // inv symmetric -> coalesced column reads
#pragma unroll 8
    for (int d = 0; d < 64; ++d) inner = fmaf(ws[OFF_INV + d * 64 + o], lds_m[d], inner);
    float p = m * inner;
#pragma unroll
    for (int mm = 32; mm; mm >>= 1) p += __shfl_xor(p, mm, 64);
    if (o == 0) ws[OFF_DIAG + b * 64 + k] = p;
  }
}

// K2: T = means@inv ; q = diag_i+diag_j-2*T_i.m_j ; adj = exp(-sqrt(max(q,1e-12))) ; AM = adj@means
__global__ __launch_bounds__(256) void k2_adj(float* __restrict__ ws)
{
  __shared__ __align__(16) float means_s[64 * 68];
  __shared__ __align__(16) float inv_s[64 * 68];
  __shared__ __align__(16) float T_s[8 * 68];
  __shared__ __align__(16) float adj_s[8 * 68];
  __shared__ float diag_s[64];
  const int b = blockIdx.x >> 3;
  const int i0 = (blockIdx.x & 7) << 3;
  const int t = threadIdx.x;
  const float* mg = ws + OFF_MEANS + b * 4096;
  for (int e = t; e < 4096; e += 256) means_s[(e >> 6) * 68 + (e & 63)] = mg[e];
  const float* ig = ws + OFF_INV;
  for (int e = t; e < 4096; e += 256) inv_s[(e >> 6) * 68 + (e & 63)] = ig[e];
  if (t < 64) diag_s[t] = ws[OFF_DIAG + b * 64 + t];
  __syncthreads();
  if (t < 128) {
    const int i = t >> 4, d0 = (t & 15) << 2;
    float4 acc = {0.f, 0.f, 0.f, 0.f};
    for (int c = 0; c < 64; ++c) {
      const float mv = means_s[(i0 + i) * 68 + c];
      const float4 iv = *(const float4*)&inv_s[c * 68 + d0];
      acc.x = fmaf(mv, iv.x, acc.x); acc.y = fmaf(mv, iv.y, acc.y);
      acc.z = fmaf(mv, iv.z, acc.z); acc.w = fmaf(mv, iv.w, acc.w);
    }
    *(float4*)&T_s[i * 68 + d0] = acc;
  }
  __syncthreads();
  {
    const int i = t >> 5, jb = t & 31;
#pragma unroll
    for (int jj = 0; jj < 2; ++jj) {
      const int j = jb + (jj << 5);
      float4 p4 = {0.f, 0.f, 0.f, 0.f};
      for (int dq = 0; dq < 64; dq += 4) {
        const float4 tv = *(const float4*)&T_s[i * 68 + dq];
        const float4 mv = *(const float4*)&means_s[j * 68 + dq];
        p4.x = fmaf(tv.x, mv.x, p4.x); p4.y = fmaf(tv.y, mv.y, p4.y);
        p4.z = fmaf(tv.z, mv.z, p4.z); p4.w = fmaf(tv.w, mv.w, p4.w);
      }
      const float p = (p4.x + p4.y) + (p4.z + p4.w);
      const float q = diag_s[i0 + i] + diag_s[j] - 2.f * p;
      adj_s[i * 68 + j] = __expf(-sqrtf(fmaxf(q, 1e-12f)));
    }
  }
  __syncthreads();
  if (t < 128) {
    const int i = t >> 4, oq = (t & 15) << 2;
    float4 am = {0.f, 0.f, 0.f, 0.f};
    for (int j = 0; j < 64; ++j) {
      const float av = adj_s[i * 68 + j];
      const float4 mv = *(const float4*)&means_s[j * 68 + oq];
      am.x = fmaf(av, mv.x, am.x); am.y = fmaf(av, mv.y, am.y);
      am.z = fmaf(av, mv.z, am.z); am.w = fmaf(av, mv.w, am.w);
    }
    *(float4*)(ws + OFF_ADJM + (size_t)(b * 64 + i0 + i) * 64 + oq) = am;
  }
}

// K3: BN partial stats of f = relu(xt + adj_means[idx]). 512 blocks: (b, o-pair oc, 2048-px tile).
__global__ __launch_bounds__(256) void k3_bnstats(const int* __restrict__ index,
                                                  float* __restrict__ ws)
{
  __shared__ float am_s[128];   // [64 k][2 o]
  __shared__ float red[4];
  const int blk = blockIdx.x, t = threadIdx.x;
  const int b = blk >> 8, oc = (blk >> 3) & 31, tile = blk & 7;
  const int o0 = oc * 2;
  if (t < 128) am_s[t] = ws[OFF_ADJM + (size_t)(b * 64 + (t >> 1)) * 64 + o0 + (t & 1)];
  if (t < 4) red[t] = 0.f;
  __syncthreads();
  const int lane = t & 63, w = t >> 6;
  const unsigned short* xtu = (const unsigned short*)(ws + OFF_XT);
  float s0 = 0.f, s1 = 0.f, q0 = 0.f, q1 = 0.f;
#pragma unroll
  for (int q = 0; q < 2; ++q) {
    const int px = tile * 2048 + (w * 2 + q) * 256 + lane * 4;
    const int4 kv = *(const int4*)(index + b * HW + px);
    const ushort4 u0 = *(const ushort4*)(xtu + (size_t)(b * 64 + o0    ) * HW + px);
    const ushort4 u1 = *(const ushort4*)(xtu + (size_t)(b * 64 + o0 + 1) * HW + px);
    const int kk[4] = {kv.x, kv.y, kv.z, kv.w};
    const float x0[4] = {bf2f(u0.x), bf2f(u0.y), bf2f(u0.z), bf2f(u0.w)};
    const float x1[4] = {bf2f(u1.x), bf2f(u1.y), bf2f(u1.z), bf2f(u1.w)};
#pragma unroll
    for (int j = 0; j < 4; ++j) {
      const float2 am = *(const float2*)&am_s[kk[j] * 2];
      const float f0 = fmaxf(x0[j] + am.x, 0.f);
      const float f1 = fmaxf(x1[j] + am.y, 0.f);
      s0 += f0; q0 = fmaf(f0, f0, q0);
      s1 += f1; q1 = fmaf(f1, f1, q1);
    }
  }
#pragma unroll
  for (int m = 1; m < 64; m <<= 1) {
    s0 += __shfl_xor(s0, m, 64); s1 += __shfl_xor(s1, m, 64);
    q0 += __shfl_xor(q0, m, 64); q1 += __shfl_xor(q1, m, 64);
  }
  if (lane == 0) {
    atomicAdd(&red[0], s0); atomicAdd(&red[1], s1);
    atomicAdd(&red[2], q0); atomicAdd(&red[3], q1);
  }
  __syncthreads();
  if (t == 0) {
    float4 v; v.x = red[0]; v.y = red[1]; v.z = red[2]; v.w = red[3];
    *(float4*)(ws + OFF_BNP + (size_t)(oc * 16 + b * 8 + tile) * 4) = v;
  }
}

// K4: redundant BN-final reduce (16 float4) per block, then out = f*scale + shift.
__global__ __launch_bounds__(256) void k4_out(const int* __restrict__ index,
    const float* __restrict__ gamma, const float* __restrict__ beta,
    const float* __restrict__ ws, float* __restrict__ out)
{
  __shared__ float am_s[128];
  __shared__ float4 tmp[16];
  __shared__ float sc_s[2], sh_s[2];
  const int blk = blockIdx.x, t = threadIdx.x;
  const int b = blk >> 8, oc = (blk >> 3) & 31, tile = blk & 7;
  const int o0 = oc * 2;
  if (t < 128) am_s[t] = ws[OFF_ADJM + (size_t)(b * 64 + (t >> 1)) * 64 + o0 + (t & 1)];
  if (t < 16) tmp[t] = *(const float4*)(ws + OFF_BNP + (size_t)(oc * 16 + t) * 4);
  if (t < 2) {   // same wave as tmp writers: per-wave LDS ordering suffices
    float s = 0.f, qq = 0.f;
#pragma unroll
    for (int i = 0; i < 16; ++i) {
      const float4 v = tmp[i];
      s  += (t == 0) ? v.x : v.y;
      qq += (t == 0) ? v.z : v.w;
    }
    const float mean = s * (1.f / 32768.f);
    const float var  = qq * (1.f / 32768.f) - mean * mean;
    const float sc = gamma[o0 + t] * rsqrtf(var + 1e-5f);
    sc_s[t] = sc;
    sh_s[t] = fmaf(-mean, sc, beta[o0 + t]);
  }
  __syncthreads();
  const int lane = t & 63, w = t >> 6;
  const unsigned short* xtu = (const unsigned short*)(ws + OFF_XT);
  const float c0 = sc_s[0], c1 = sc_s[1], h0 = sh_s[0], h1 = sh_s[1];
#pragma unroll
  for (int q = 0; q < 2; ++q) {
    const int px = tile * 2048 + (w * 2 + q) * 256 + lane * 4;
    const int4 kv = *(const int4*)(index + b * HW + px);
    const ushort4 u0 = *(const ushort4*)(xtu + (size_t)(b * 64 + o0    ) * HW + px);
    const ushort4 u1 = *(const ushort4*)(xtu + (size_t)(b * 64 + o0 + 1) * HW + px);
    const int kk[4] = {kv.x, kv.y, kv.z, kv.w};
    const float x0[4] = {bf2f(u0.x), bf2f(u0.y), bf2f(u0.z), bf2f(u0.w)};
    const float x1[4] = {bf2f(u1.x), bf2f(u1.y), bf2f(u1.z), bf2f(u1.w)};
    float4 o4a, o4b;
    float* oa = (float*)&o4a; float* ob = (float*)&o4b;
#pragma unroll
    for (int j = 0; j < 4; ++j) {
      const float2 am = *(const float2*)&am_s[kk[j] * 2];
      oa[j] = fmaf(fmaxf(x0[j] + am.x, 0.f), c0, h0);
      ob[j] = fmaf(fmaxf(x1[j] + am.y, 0.f), c1, h1);
    }
    *(float4*)(out + (size_t)(b * 64 + o0    ) * HW + px) = o4a;
    *(float4*)(out + (size_t)(b * 64 + o0 + 1) * HW + px) = o4b;
  }
}

extern "C" void kernel_launch(void* const* d_in, const int* in_sizes, int n_in,
                              void* d_out, int out_size, void* d_ws, size_t ws_size,
                              hipStream_t stream) {
  const float* x     = (const float*)d_in[0];
  const int*   index = (const int*)d_in[1];
  const float* Wft   = (const float*)d_in[2];
  const float* Wm    = (const float*)d_in[3];
  const float* gamma = (const float*)d_in[4];
  const float* beta  = (const float*)d_in[5];
  float* ws  = (float*)d_ws;
  float* out = (float*)d_out;

  k1_xt_bins_inv<<<513, 256, 0, stream>>>(x, index, Wft, Wm, ws);
  k15_means_diag<<<128, 1024, 0, stream>>>(ws);
  k2_adj<<<16, 256, 0, stream>>>(ws);
  k3_bnstats<<<512, 256, 0, stream>>>(index, ws);
  k4_out<<<512, 256, 0, stream>>>(index, gamma, beta, ws, out);
}

// Round 8
// 120.064 us; speedup vs baseline: 2.4824x; 1.0807x over previous
//
#include <hip/hip_runtime.h>
#include <hip/hip_bf16.h>

// Problem constants
#define CIN   128
#define COUT  64
#define HW    16384   // 128*128

typedef __hip_bfloat16 bf16;

// Workspace layout (float offsets) — total 2,152,576 floats = 8.6 MB
#define OFF_XT    0u          // bf16[2][64][16384]  xt            (1048576 f-equiv)
#define OFF_PS    1048576u    // bf16[512 blk][64 k][64 o] partial bin sums (1048576 f-equiv)
#define OFF_PC    2097152u    // f32 [2][64][256]    partial bin counts
#define OFF_MEANS 2129920u    // f32 [2][64][64]
#define OFF_DIAG  2138112u    // f32 [2][64]         m^T C^-1 m
#define OFF_INV   2138240u    // f32 [64][64]        inv(cov) (symmetric)
#define OFF_ADJM  2142336u    // f32 [2][64][64]     adj @ means
#define OFF_BNP   2150528u    // f32 [32 oc][16 b*tile] float4 {s0,s1,ss0,ss1}

__device__ __forceinline__ unsigned short f2bfu(float f) {
  union { bf16 h; unsigned short u; } cv; cv.h = __float2bfloat16(f); return cv.u;
}
__device__ __forceinline__ float bf2f(unsigned short u) {
  union { unsigned int i; float f; } cv; cv.i = ((unsigned int)u) << 16; return cv.f;
}

// K1: xt = einsum('bchw,co->bohw') (bf16 out) + per-block bin partials; block 0 = inv(Wm Wm^T).
// Inverse: BLOCKED Gauss-Jordan, 16 panels of 4 pivots (R7 lesson: 64 scalar steps = 64
// barrier+LDS latency chains ~41us on a draining/downclocked GPU; 16 panels x 128 reg-FMA
// each ~5us, hidden under the ~16us einsum window while clocks are still high).
__global__ __launch_bounds__(256, 2) void k1_xt_bins_inv(
    const float* __restrict__ x, const int* __restrict__ index,
    const float* __restrict__ Wft, const float* __restrict__ Wm,
    float* __restrict__ ws)
{
  __shared__ __align__(16) float smem[16384];   // 64 KB
  const int blk = blockIdx.x, tid = threadIdx.x;
  if (blk != 0) {
    float* xl = smem;          // [128 c][64 px]
    float* wl = smem + 8192;   // [128 c][64 o]
    const int eb = blk - 1;
    const int b = eb >> 8, ps = eb & 255;
    // ---- stage x slab (64 px x 128 c) and all of Wft, bulk-coalesced
    const float* xg = x + (size_t)b * CIN * HW + ps * 64;
#pragma unroll
    for (int j = 0; j < 8; ++j) {
      const int fj = j * 256 + tid;            // float4 id
      const int c = fj >> 4, q4 = (fj & 15) * 4;
      *(float4*)&xl[c * 64 + q4] = *(const float4*)(xg + (size_t)c * HW + q4);
      *(float4*)&wl[c * 64 + q4] = *(const float4*)(Wft + c * 64 + q4);
    }
    __syncthreads();
    // ---- register-tiled compute: thread = 4px x 4o
    const int px_grp = tid & 15, o_grp = tid >> 4;
    const int px = ps * 64 + px_grp * 4, o0 = o_grp * 4;
    float acc[16];
#pragma unroll
    for (int j = 0; j < 16; ++j) acc[j] = 0.f;
#pragma unroll 8
    for (int c = 0; c < 128; ++c) {
      const float4 xv = *(const float4*)&xl[c * 64 + px_grp * 4];
      const float4 wv = *(const float4*)&wl[c * 64 + o0];
      acc[ 0]=fmaf(xv.x,wv.x,acc[ 0]); acc[ 1]=fmaf(xv.y,wv.x,acc[ 1]);
      acc[ 2]=fmaf(xv.z,wv.x,acc[ 2]); acc[ 3]=fmaf(xv.w,wv.x,acc[ 3]);
      acc[ 4]=fmaf(xv.x,wv.y,acc[ 4]); acc[ 5]=fmaf(xv.y,wv.y,acc[ 5]);
      acc[ 6]=fmaf(xv.z,wv.y,acc[ 6]); acc[ 7]=fmaf(xv.w,wv.y,acc[ 7]);
      acc[ 8]=fmaf(xv.x,wv.z,acc[ 8]); acc[ 9]=fmaf(xv.y,wv.z,acc[ 9]);
      acc[10]=fmaf(xv.z,wv.z,acc[10]); acc[11]=fmaf(xv.w,wv.z,acc[11]);
      acc[12]=fmaf(xv.x,wv.w,acc[12]); acc[13]=fmaf(xv.y,wv.w,acc[13]);
      acc[14]=fmaf(xv.z,wv.w,acc[14]); acc[15]=fmaf(xv.w,wv.w,acc[15]);
    }
    // ---- write xt (bf16)
    unsigned short* xtu = (unsigned short*)(ws + OFF_XT);
#pragma unroll
    for (int oj = 0; oj < 4; ++oj) {
      ushort4 u;
      u.x = f2bfu(acc[oj*4+0]); u.y = f2bfu(acc[oj*4+1]);
      u.z = f2bfu(acc[oj*4+2]); u.w = f2bfu(acc[oj*4+3]);
      *(ushort4*)(xtu + (size_t)(b * 64 + o0 + oj) * HW + px) = u;
    }
    // ---- bin partials (reuse LDS after compute done)
    const int4 kv = *(const int4*)(index + b * HW + px);
    const int kk[4] = {kv.x, kv.y, kv.z, kv.w};
    __syncthreads();                       // all LDS compute reads done
    float* bins = smem;                    // [64 k][68] padded
    float* cnt  = smem + 64 * 68;          // [64]
    for (int i = tid; i < 64 * 68 + 64; i += 256) smem[i] = 0.f;
    __syncthreads();
#pragma unroll
    for (int pj = 0; pj < 4; ++pj) {
      const int kb = kk[pj] * 68 + o0;
      atomicAdd(&bins[kb    ], acc[ 0 + pj]);
      atomicAdd(&bins[kb + 1], acc[ 4 + pj]);
      atomicAdd(&bins[kb + 2], acc[ 8 + pj]);
      atomicAdd(&bins[kb + 3], acc[12 + pj]);
    }
    if (o_grp == 0) {   // exactly one thread per px (R3 lesson: guard the o replication)
#pragma unroll
      for (int pj = 0; pj < 4; ++pj) atomicAdd(&cnt[kk[pj]], 1.f);
    }
    __syncthreads();
    // ---- dump partials as bf16: [64 k][64 o]
    unsigned short* pb = (unsigned short*)(ws + OFF_PS) + (size_t)eb * 4096;
    {
      const int k = tid >> 2, ob = (tid & 3) * 16;
#pragma unroll
      for (int q = 0; q < 4; ++q) {
        const float4 v = *(const float4*)&bins[k * 68 + ob + q * 4];
        ushort4 u;
        u.x = f2bfu(v.x); u.y = f2bfu(v.y); u.z = f2bfu(v.z); u.w = f2bfu(v.w);
        *(ushort4*)(pb + k * 64 + ob + q * 4) = u;
      }
    }
    if (tid < 64) ws[OFF_PC + (size_t)(b * 64 + tid) * 256 + ps] = cnt[tid];
  } else {
    // ---- inverse block (block 0): cov = Wm Wm^T in regs (thread = 4x4 tile),
    //      then blocked Gauss-Jordan with 4x4 pivot panels (16 panels, 1 barrier each).
    float* wm = smem;             // [64][68]
    float* Rb = smem + 8192;      // [2][4][64]  panel-row strips (dbuf)
    float* Cb = smem + 8704;      // [2][64][4]  panel-col strips (dbuf)
    for (int e = tid; e < 4096; e += 256) wm[(e >> 6) * 68 + (e & 63)] = Wm[e];
    __syncthreads();
    const int ig = tid >> 4, jg = tid & 15;
    const int i0 = ig << 2, j0 = jg << 2;
    float c4[16];
#pragma unroll
    for (int q = 0; q < 16; ++q) c4[q] = 0.f;
    for (int cq = 0; cq < 64; cq += 4) {
      float4 a[4], bb[4];
#pragma unroll
      for (int ii = 0; ii < 4; ++ii) a[ii]  = *(const float4*)&wm[(i0+ii)*68 + cq];
#pragma unroll
      for (int jj = 0; jj < 4; ++jj) bb[jj] = *(const float4*)&wm[(j0+jj)*68 + cq];
#pragma unroll
      for (int ii = 0; ii < 4; ++ii)
#pragma unroll
        for (int jj = 0; jj < 4; ++jj)
          c4[ii*4+jj] = fmaf(a[ii].x, bb[jj].x, fmaf(a[ii].y, bb[jj].y,
                        fmaf(a[ii].z, bb[jj].z, fmaf(a[ii].w, bb[jj].w, c4[ii*4+jj]))));
    }
    __syncthreads();   // wm reads done
    __builtin_amdgcn_s_setprio(3);   // win arbitration vs co-resident einsum waves
    int buf = 0;
#pragma unroll 1   // MUST stay rolled (R5/R6 lesson: unrolled copies = I$ thrash)
    for (int p = 0; p < 16; ++p) {
      const int P = p << 2;
      float* Rp = Rb + buf * 256;    // [4][64]: R[r][j] = A[P+r][j]
      float* Cp = Cb + buf * 256;    // [64][4]: C[i][r] = A[i][P+r]
      if (ig == p) {                 // own tile rows are panel rows -> publish R strip
#pragma unroll
        for (int r = 0; r < 4; ++r) {
          float4 t; t.x = c4[r*4+0]; t.y = c4[r*4+1]; t.z = c4[r*4+2]; t.w = c4[r*4+3];
          *(float4*)&Rp[r * 64 + j0] = t;
        }
      }
      if (jg == p) {                 // own tile cols are panel cols -> publish C strip
#pragma unroll
        for (int ii = 0; ii < 4; ++ii) {
          float4 t; t.x = c4[ii*4+0]; t.y = c4[ii*4+1]; t.z = c4[ii*4+2]; t.w = c4[ii*4+3];
          *(float4*)&Cp[(i0 + ii) * 4] = t;
        }
      }
      __syncthreads();               // single barrier per panel (dbuf makes it safe)
      float dd[16], cc[16], rr[16];
#pragma unroll
      for (int r = 0; r < 4; ++r) *(float4*)&dd[r * 4] = *(const float4*)&Rp[r * 64 + P];
#pragma unroll
      for (int ii = 0; ii < 4; ++ii) *(float4*)&cc[ii * 4] = *(const float4*)&Cp[(i0 + ii) * 4];
#pragma unroll
      for (int r = 0; r < 4; ++r) *(float4*)&rr[r * 4] = *(const float4*)&Rp[r * 64 + j0];
      // ---- Dinv: static 4x4 Gauss-Jordan in registers (redundant per thread)
#pragma unroll
      for (int k = 0; k < 4; ++k) {
        const float rp = __builtin_amdgcn_rcpf(dd[k * 4 + k]);
        float ai[4], s[4];
#pragma unroll
        for (int j = 0; j < 4; ++j) s[j] = dd[k * 4 + j];
#pragma unroll
        for (int i = 0; i < 4; ++i) ai[i] = (i == k) ? (rp - 1.0f) : (-dd[i * 4 + k] * rp);
#pragma unroll
        for (int i = 0; i < 4; ++i)
#pragma unroll
          for (int j = 0; j < 4; ++j) dd[i * 4 + j] = fmaf(ai[i], s[j], dd[i * 4 + j]);
#pragma unroll
        for (int i = 0; i < 4; ++i) dd[i * 4 + k] = (i == k) ? rp : ai[i];
      }
      // ---- T = C · Dinv
      float T[16];
#pragma unroll
      for (int ii = 0; ii < 4; ++ii)
#pragma unroll
        for (int c = 0; c < 4; ++c) {
          float t = cc[ii*4+0] * dd[0*4+c];
          t = fmaf(cc[ii*4+1], dd[1*4+c], t);
          t = fmaf(cc[ii*4+2], dd[2*4+c], t);
          t = fmaf(cc[ii*4+3], dd[3*4+c], t);
          T[ii*4+c] = t;
        }
      // ---- apply block-GJ update to own tile
      if (ig == p && jg == p) {
#pragma unroll
        for (int q = 0; q < 16; ++q) c4[q] = dd[q];          // A_pp = Dinv
      } else if (ig == p) {
#pragma unroll
        for (int r = 0; r < 4; ++r)
#pragma unroll
          for (int jj = 0; jj < 4; ++jj) {                    // A_pj = Dinv · R
            float t = dd[r*4+0] * rr[0*4+jj];
            t = fmaf(dd[r*4+1], rr[1*4+jj], t);
            t = fmaf(dd[r*4+2], rr[2*4+jj], t);
            t = fmaf(dd[r*4+3], rr[3*4+jj], t);
            c4[r*4+jj] = t;
          }
      } else if (jg == p) {
#pragma unroll
        for (int q = 0; q < 16; ++q) c4[q] = -T[q];           // A_ip = -C · Dinv
      } else {
#pragma unroll
        for (int ii = 0; ii < 4; ++ii)
#pragma unroll
          for (int jj = 0; jj < 4; ++jj) {                    // A_ij -= T · R
            float t = c4[ii*4+jj];
            t = fmaf(-T[ii*4+0], rr[0*4+jj], t);
            t = fmaf(-T[ii*4+1], rr[1*4+jj], t);
            t = fmaf(-T[ii*4+2], rr[2*4+jj], t);
            t = fmaf(-T[ii*4+3], rr[3*4+jj], t);
            c4[ii*4+jj] = t;
          }
      }
      buf ^= 1;
    }
    __builtin_amdgcn_s_setprio(0);
#pragma unroll
    for (int ii = 0; ii < 4; ++ii)
#pragma unroll
      for (int jj = 0; jj < 4; ++jj)
        ws[OFF_INV + (size_t)(i0 + ii) * 64 + j0 + jj] = c4[ii*4+jj];
  }
}

// K1.5: reduce bin partials -> means; diag[b][k] = m^T C^-1 m. 128 blocks x 1024 thr.
__global__ __launch_bounds__(1024) void k15_means_diag(float* __restrict__ ws)
{
  __shared__ float red[1024];
  __shared__ float lds_c[4];
  __shared__ float lds_m[64];
  const int blk = blockIdx.x, t = threadIdx.x;
  const int b = blk >> 6, k = blk & 63;
  const int o = t & 63, chunk = t >> 6;
  const unsigned short* psu = (const unsigned short*)(ws + OFF_PS);
  float s = 0.f;
#pragma unroll
  for (int i = 0; i < 16; ++i) {
    const int slab = chunk * 16 + i;
    s += bf2f(psu[(size_t)(b * 256 + slab) * 4096 + k * 64 + o]);
  }
  red[chunk * 64 + o] = s;
  float cv = 0.f;
  if (t < 256) cv = ws[OFF_PC + (size_t)(b * 64 + k) * 256 + t];
#pragma unroll
  for (int m = 32; m; m >>= 1) cv += __shfl_xor(cv, m, 64);
  if (t < 256 && (t & 63) == 0) lds_c[t >> 6] = cv;
  __syncthreads();
  if (t < 64) {
    float m_raw = 0.f;
#pragma unroll
    for (int ch = 0; ch < 16; ++ch) m_raw += red[ch * 64 + o];
    const float cnt = lds_c[0] + lds_c[1] + lds_c[2] + lds_c[3];
    const float denom = cnt + ((cnt == 0.f) ? 1.f : 0.f);
    const float m = m_raw / denom;
    ws[OFF_MEANS + (size_t)(b * 64 + k) * 64 + o] = m;
    lds_m[o] = m;
    float inner = 0.f;  // inv symmetric -> coalesced column reads
#pragma unroll 8
    for (int d = 0; d < 64; ++d) inner = fmaf(ws[OFF_INV + d * 64 + o], lds_m[d], inner);
    float p = m * inner;
#pragma unroll
    for (int mm = 32; mm; mm >>= 1) p += __shfl_xor(p, mm, 64);
    if (o == 0) ws[OFF_DIAG + b * 64 + k] = p;
  }
}

// K2: T = means@inv ; q = diag_i+diag_j-2*T_i.m_j ; adj = exp(-sqrt(max(q,1e-12))) ; AM = adj@means
__global__ __launch_bounds__(256) void k2_adj(float* __restrict__ ws)
{
  __shared__ __align__(16) float means_s[64 * 68];
  __shared__ __align__(16) float inv_s[64 * 68];
  __shared__ __align__(16) float T_s[8 * 68];
  __shared__ __align__(16) float adj_s[8 * 68];
  __shared__ float diag_s[64];
  const int b = blockIdx.x >> 3;
  const int i0 = (blockIdx.x & 7) << 3;
  const int t = threadIdx.x;
  const float* mg = ws + OFF_MEANS + b * 4096;
  for (int e = t; e < 4096; e += 256) means_s[(e >> 6) * 68 + (e & 63)] = mg[e];
  const float* ig = ws + OFF_INV;
  for (int e = t; e < 4096; e += 256) inv_s[(e >> 6) * 68 + (e & 63)] = ig[e];
  if (t < 64) diag_s[t] = ws[OFF_DIAG + b * 64 + t];
  __syncthreads();
  if (t < 128) {
    const int i = t >> 4, d0 = (t & 15) << 2;
    float4 acc = {0.f, 0.f, 0.f, 0.f};
    for (int c = 0; c < 64; ++c) {
      const float mv = means_s[(i0 + i) * 68 + c];
      const float4 iv = *(const float4*)&inv_s[c * 68 + d0];
      acc.x = fmaf(mv, iv.x, acc.x); acc.y = fmaf(mv, iv.y, acc.y);
      acc.z = fmaf(mv, iv.z, acc.z); acc.w = fmaf(mv, iv.w, acc.w);
    }
    *(float4*)&T_s[i * 68 + d0] = acc;
  }
  __syncthreads();
  {
    const int i = t >> 5, jb = t & 31;
#pragma unroll
    for (int jj = 0; jj < 2; ++jj) {
      const int j = jb + (jj << 5);
      float4 p4 = {0.f, 0.f, 0.f, 0.f};
      for (int dq = 0; dq < 64; dq += 4) {
        const float4 tv = *(const float4*)&T_s[i * 68 + dq];
        const float4 mv = *(const float4*)&means_s[j * 68 + dq];
        p4.x = fmaf(tv.x, mv.x, p4.x); p4.y = fmaf(tv.y, mv.y, p4.y);
        p4.z = fmaf(tv.z, mv.z, p4.z); p4.w = fmaf(tv.w, mv.w, p4.w);
      }
      const float p = (p4.x + p4.y) + (p4.z + p4.w);
      const float q = diag_s[i0 + i] + diag_s[j] - 2.f * p;
      adj_s[i * 68 + j] = __expf(-sqrtf(fmaxf(q, 1e-12f)));
    }
  }
  __syncthreads();
  if (t < 128) {
    const int i = t >> 4, oq = (t & 15) << 2;
    float4 am = {0.f, 0.f, 0.f, 0.f};
    for (int j = 0; j < 64; ++j) {
      const float av = adj_s[i * 68 + j];
      const float4 mv = *(const float4*)&means_s[j * 68 + oq];
      am.x = fmaf(av, mv.x, am.x); am.y = fmaf(av, mv.y, am.y);
      am.z = fmaf(av, mv.z, am.z); am.w = fmaf(av, mv.w, am.w);
    }
    *(float4*)(ws + OFF_ADJM + (size_t)(b * 64 + i0 + i) * 64 + oq) = am;
  }
}

// K3: BN partial stats of f = relu(xt + adj_means[idx]). 512 blocks: (b, o-pair oc, 2048-px tile).
__global__ __launch_bounds__(256) void k3_bnstats(const int* __restrict__ index,
                                                  float* __restrict__ ws)
{
  __shared__ float am_s[128];   // [64 k][2 o]
  __shared__ float red[4];
  const int blk = blockIdx.x, t = threadIdx.x;
  const int b = blk >> 8, oc = (blk >> 3) & 31, tile = blk & 7;
  const int o0 = oc * 2;
  if (t < 128) am_s[t] = ws[OFF_ADJM + (size_t)(b * 64 + (t >> 1)) * 64 + o0 + (t & 1)];
  if (t < 4) red[t] = 0.f;
  __syncthreads();
  const int lane = t & 63, w = t >> 6;
  const unsigned short* xtu = (const unsigned short*)(ws + OFF_XT);
  float s0 = 0.f, s1 = 0.f, q0 = 0.f, q1 = 0.f;
#pragma unroll
  for (int q = 0; q < 2; ++q) {
    const int px = tile * 2048 + (w * 2 + q) * 256 + lane * 4;
    const int4 kv = *(const int4*)(index + b * HW + px);
    const ushort4 u0 = *(const ushort4*)(xtu + (size_t)(b * 64 + o0    ) * HW + px);
    const ushort4 u1 = *(const ushort4*)(xtu + (size_t)(b * 64 + o0 + 1) * HW + px);
    const int kk[4] = {kv.x, kv.y, kv.z, kv.w};
    const float x0[4] = {bf2f(u0.x), bf2f(u0.y), bf2f(u0.z), bf2f(u0.w)};
    const float x1[4] = {bf2f(u1.x), bf2f(u1.y), bf2f(u1.z), bf2f(u1.w)};
#pragma unroll
    for (int j = 0; j < 4; ++j) {
      const float2 am = *(const float2*)&am_s[kk[j] * 2];
      const float f0 = fmaxf(x0[j] + am.x, 0.f);
      const float f1 = fmaxf(x1[j] + am.y, 0.f);
      s0 += f0; q0 = fmaf(f0, f0, q0);
      s1 += f1; q1 = fmaf(f1, f1, q1);
    }
  }
#pragma unroll
  for (int m = 1; m < 64; m <<= 1) {
    s0 += __shfl_xor(s0, m, 64); s1 += __shfl_xor(s1, m, 64);
    q0 += __shfl_xor(q0, m, 64); q1 += __shfl_xor(q1, m, 64);
  }
  if (lane == 0) {
    atomicAdd(&red[0], s0); atomicAdd(&red[1], s1);
    atomicAdd(&red[2], q0); atomicAdd(&red[3], q1);
  }
  __syncthreads();
  if (t == 0) {
    float4 v; v.x = red[0]; v.y = red[1]; v.z = red[2]; v.w = red[3];
    *(float4*)(ws + OFF_BNP + (size_t)(oc * 16 + b * 8 + tile) * 4) = v;
  }
}

// K4: redundant BN-final reduce (16 float4) per block, then out = f*scale + shift.
__global__ __launch_bounds__(256) void k4_out(const int* __restrict__ index,
    const float* __restrict__ gamma, const float* __restrict__ beta,
    const float* __restrict__ ws, float* __restrict__ out)
{
  __shared__ float am_s[128];
  __shared__ float4 tmp[16];
  __shared__ float sc_s[2], sh_s[2];
  const int blk = blockIdx.x, t = threadIdx.x;
  const int b = blk >> 8, oc = (blk >> 3) & 31, tile = blk & 7;
  const int o0 = oc * 2;
  if (t < 128) am_s[t] = ws[OFF_ADJM + (size_t)(b * 64 + (t >> 1)) * 64 + o0 + (t & 1)];
  if (t < 16) tmp[t] = *(const float4*)(ws + OFF_BNP + (size_t)(oc * 16 + t) * 4);
  if (t < 2) {   // same wave as tmp writers: per-wave LDS ordering suffices
    float s = 0.f, qq = 0.f;
#pragma unroll
    for (int i = 0; i < 16; ++i) {
      const float4 v = tmp[i];
      s  += (t == 0) ? v.x : v.y;
      qq += (t == 0) ? v.z : v.w;
    }
    const float mean = s * (1.f / 32768.f);
    const float var  = qq * (1.f / 32768.f) - mean * mean;
    const float sc = gamma[o0 + t] * rsqrtf(var + 1e-5f);
    sc_s[t] = sc;
    sh_s[t] = fmaf(-mean, sc, beta[o0 + t]);
  }
  __syncthreads();
  const int lane = t & 63, w = t >> 6;
  const unsigned short* xtu = (const unsigned short*)(ws + OFF_XT);
  const float c0 = sc_s[0], c1 = sc_s[1], h0 = sh_s[0], h1 = sh_s[1];
#pragma unroll
  for (int q = 0; q < 2; ++q) {
    const int px = tile * 2048 + (w * 2 + q) * 256 + lane * 4;
    const int4 kv = *(const int4*)(index + b * HW + px);
    const ushort4 u0 = *(const ushort4*)(xtu + (size_t)(b * 64 + o0    ) * HW + px);
    const ushort4 u1 = *(const ushort4*)(xtu + (size_t)(b * 64 + o0 + 1) * HW + px);
    const int kk[4] = {kv.x, kv.y, kv.z, kv.w};
    const float x0[4] = {bf2f(u0.x), bf2f(u0.y), bf2f(u0.z), bf2f(u0.w)};
    const float x1[4] = {bf2f(u1.x), bf2f(u1.y), bf2f(u1.z), bf2f(u1.w)};
    float4 o4a, o4b;
    float* oa = (float*)&o4a; float* ob = (float*)&o4b;
#pragma unroll
    for (int j = 0; j < 4; ++j) {
      const float2 am = *(const float2*)&am_s[kk[j] * 2];
      oa[j] = fmaf(fmaxf(x0[j] + am.x, 0.f), c0, h0);
      ob[j] = fmaf(fmaxf(x1[j] + am.y, 0.f), c1, h1);
    }
    *(float4*)(out + (size_t)(b * 64 + o0    ) * HW + px) = o4a;
    *(float4*)(out + (size_t)(b * 64 + o0 + 1) * HW + px) = o4b;
  }
}

extern "C" void kernel_launch(void* const* d_in, const int* in_sizes, int n_in,
                              void* d_out, int out_size, void* d_ws, size_t ws_size,
                              hipStream_t stream) {
  const float* x     = (const float*)d_in[0];
  const int*   index = (const int*)d_in[1];
  const float* Wft   = (const float*)d_in[2];
  const float* Wm    = (const float*)d_in[3];
  const float* gamma = (const float*)d_in[4];
  const float* beta  = (const float*)d_in[5];
  float* ws  = (float*)d_ws;
  float* out = (float*)d_out;

  k1_xt_bins_inv<<<513, 256, 0, stream>>>(x, index, Wft, Wm, ws);
  k15_means_diag<<<128, 1024, 0, stream>>>(ws);
  k2_adj<<<16, 256, 0, stream>>>(ws);
  k3_bnstats<<<512, 256, 0, stream>>>(index, ws);
  k4_out<<<512, 256, 0, stream>>>(index, gamma, beta, ws, out);
}